// Round 1
// baseline (514.113 us; speedup 1.0000x reference)
//
#include <hip/hip_runtime.h>

// Dims
#define NB 8
#define NC 32
#define NCP 33
#define NW 256
#define NH 128
#define NX 720
#define NY 361

typedef __attribute__((ext_vector_type(8))) short  short8;
typedef __attribute__((ext_vector_type(4))) float  f32x4;

// fp32 -> bf16 round-to-nearest-even
static __device__ __forceinline__ unsigned short f2bf(float f) {
    union { float f; unsigned int u; } v; v.f = f;
    unsigned int r = (v.u + 0x7FFFu + ((v.u >> 16) & 1u)) >> 16;
    return (unsigned short)r;
}

// K1: w0t[b][x][w] bf16  (A-operand layout for stage1: m=x, k=w contiguous)
__global__ __launch_bounds__(256) void rbf_w0_kernel(
    const float* __restrict__ lon_in, const float* __restrict__ lon_out,
    const float* __restrict__ ls, unsigned short* __restrict__ w0t)
{
    int idx = blockIdx.x * 256 + threadIdx.x;   // exact grid: 8*720*256
    int w = idx & (NW - 1);
    int r = idx >> 8;
    int x = r % NX;
    int b = r / NX;
    float l = ls[0];
    float inv = -0.5f / (l * l);
    float d = lon_in[b * NW + w] - lon_out[b * NX + x];
    w0t[idx] = f2bf(__expf(inv * d * d));
}

// K2: w1t[b][y][h] bf16  (B-operand layout for stage2: n=y rows, k=h contiguous)
__global__ __launch_bounds__(256) void rbf_w1_kernel(
    const float* __restrict__ lat_in, const float* __restrict__ lat_out,
    const float* __restrict__ ls, unsigned short* __restrict__ w1t)
{
    int idx = blockIdx.x * 256 + threadIdx.x;   // exact grid: 8*361*128
    int h = idx & (NH - 1);
    int r = idx >> 7;
    int y = r % NY;
    int b = r / NY;
    float l = ls[0];
    float inv = -0.5f / (l * l);
    float d = lat_in[b * NH + h] - lat_out[b * NY + y];
    w1t[idx] = f2bf(__expf(inv * d * d));
}

// K3: wtT[b][c(33)][h(128)][w(256)] bf16 — transposed, NaN-fixed, c=0 = density mask.
__global__ __launch_bounds__(256) void prep_wtT_kernel(
    const float* __restrict__ wt, unsigned short* __restrict__ wtT)
{
    __shared__ float tile[64 * 129];
    const int bc = blockIdx.z;
    const int b = bc / NCP;
    const int c = bc - b * NCP;
    const int w0 = blockIdx.x * 64;
    const bool dens = (c == 0);
    const float* src = wt + ((size_t)b * NC + (dens ? 0 : (c - 1))) * (NW * NH);

    const int r4 = threadIdx.x >> 5;   // 0..7
    const int c4 = threadIdx.x & 31;   // float4 col
    #pragma unroll
    for (int p = 0; p < 8; ++p) {
        int r = r4 + p * 8;
        float4 v = *(const float4*)&src[(size_t)(w0 + r) * NH + c4 * 4];
        float o0 = (v.x != v.x) ? 0.f : (dens ? 1.f : v.x);
        float o1 = (v.y != v.y) ? 0.f : (dens ? 1.f : v.y);
        float o2 = (v.z != v.z) ? 0.f : (dens ? 1.f : v.z);
        float o3 = (v.w != v.w) ? 0.f : (dens ? 1.f : v.w);
        float* tp = &tile[r * 129 + c4 * 4];
        tp[0] = o0; tp[1] = o1; tp[2] = o2; tp[3] = o3;
    }
    __syncthreads();

    unsigned short* dst = wtT + (size_t)bc * (NH * NW);
    #pragma unroll
    for (int p = 0; p < 4; ++p) {
        int ch = threadIdx.x + p * 256;
        int wc = ch & 7;          // which 8-w chunk in this 64-w tile
        int h  = ch >> 3;         // 0..127
        unsigned int u[4];
        #pragma unroll
        for (int j = 0; j < 4; ++j) {
            unsigned int lo = f2bf(tile[(wc * 8 + 2 * j    ) * 129 + h]);
            unsigned int hi = f2bf(tile[(wc * 8 + 2 * j + 1) * 129 + h]);
            u[j] = lo | (hi << 16);
        }
        uint4 q = make_uint4(u[0], u[1], u[2], u[3]);
        *(uint4*)&dst[(size_t)h * NW + w0 + wc * 8] = q;
    }
}

// Fused stage1+stage2: one block = one 64-row x-tile of one (b,c).
// Phase 1: T[64][128] = w0t[b][x-tile][:256] * wtT[bc][:128][:256]^T  -> LDS (bf16)
// Phase 2: out[bc][x-tile][:361] = T * w1t[b][:361][:128]^T, 6 y-chunks of 64.
// DIV=false: c=0 density plane (grid 12 x NB). DIV=true: c=1..32, divide by
// clipped density read from out plane 0 (grid 12 x NB*NC).
template <bool DIV>
__global__ __launch_bounds__(256) void fused_stage(
    const unsigned short* __restrict__ w0t,
    const unsigned short* __restrict__ wtT,
    const unsigned short* __restrict__ w1t,
    float* __restrict__ out)
{
    __shared__ __align__(16) unsigned short T[64 * 136];            // 17.4 KB
    __shared__ __align__(16) unsigned short S[64 * 72 + 128 * 72];  // 27.6 KB union

    int b, c;
    if (DIV) { b = blockIdx.y >> 5; c = 1 + (blockIdx.y & 31); }
    else     { b = blockIdx.y;      c = 0; }
    const int bc = b * NCP + c;
    const int x0 = blockIdx.x * 64;

    const int tid  = threadIdx.x;
    const int lane = tid & 63;
    const int wv   = tid >> 6;
    const int q    = lane >> 4;
    const int ln   = lane & 15;

    const unsigned short* Ap = w0t + (size_t)b * NX * NW;
    const unsigned short* Bp = wtT + (size_t)bc * NH * NW;
    const unsigned short* Vp = w1t + (size_t)b * NY * NH;

    // ---------------- Phase 1 ----------------
    unsigned short* As = S;            // [64][72]  x-rows, k=w chunk
    unsigned short* Bs = S + 64 * 72;  // [128][72] h-rows, k=w chunk

    const int mw1 = (wv & 1) * 32;     // x quadrant (2 m-tiles of 16)
    const int nh1 = (wv >> 1) * 64;    // h half (4 n-tiles of 16)

    f32x4 acc1[2][4];
    #pragma unroll
    for (int i = 0; i < 2; ++i)
        #pragma unroll
        for (int j = 0; j < 4; ++j)
            acc1[i][j] = (f32x4){0.f, 0.f, 0.f, 0.f};

    const int ar  = tid >> 2;          // 0..63
    const int ac  = (tid & 3) * 16;    // 0/16/32/48 (shorts)
    int xr = x0 + ar; if (xr > NX - 1) xr = NX - 1;
    const int brr = tid >> 1;          // 0..127
    const int bcc = (tid & 1) * 32;    // 0/32 (shorts)

    for (int k0 = 0; k0 < NW; k0 += 64) {
        const unsigned short* Arow = Ap + (size_t)xr * NW + k0 + ac;
        *(uint4*)&As[ar * 72 + ac    ] = *(const uint4*)&Arow[0];
        *(uint4*)&As[ar * 72 + ac + 8] = *(const uint4*)&Arow[8];
        const unsigned short* Brow = Bp + (size_t)brr * NW + k0 + bcc;
        #pragma unroll
        for (int j = 0; j < 4; ++j)
            *(uint4*)&Bs[brr * 72 + bcc + j * 8] = *(const uint4*)&Brow[j * 8];
        __syncthreads();
        #pragma unroll
        for (int ki = 0; ki < 2; ++ki) {
            const int ko = ki * 32 + q * 8;
            short8 a0 = *(const short8*)&As[(mw1      + ln) * 72 + ko];
            short8 a1 = *(const short8*)&As[(mw1 + 16 + ln) * 72 + ko];
            #pragma unroll
            for (int nn = 0; nn < 4; ++nn) {
                short8 bb = *(const short8*)&Bs[(nh1 + nn * 16 + ln) * 72 + ko];
                acc1[0][nn] = __builtin_amdgcn_mfma_f32_16x16x32_bf16(a0, bb, acc1[0][nn], 0, 0, 0);
                acc1[1][nn] = __builtin_amdgcn_mfma_f32_16x16x32_bf16(a1, bb, acc1[1][nn], 0, 0, 0);
            }
        }
        __syncthreads();
    }

    // Write T quadrant (each wave owns disjoint 32x64 region).
    #pragma unroll
    for (int nn = 0; nn < 4; ++nn) {
        const int col = nh1 + nn * 16 + ln;
        #pragma unroll
        for (int mi = 0; mi < 2; ++mi) {
            #pragma unroll
            for (int reg = 0; reg < 4; ++reg) {
                int row = mw1 + mi * 16 + q * 4 + reg;
                T[row * 136 + col] = f2bf(acc1[mi][nn][reg]);
            }
        }
    }
    __syncthreads();

    // ---------------- Phase 2 ----------------
    unsigned short* Bs2 = S;           // [64][136] y-rows, k=h full
    const int mw2 = (wv & 1) * 32;
    const int nw2 = (wv >> 1) * 32;

    const size_t plane = (size_t)NX * NY;
    float* Cp = out + (size_t)bc * plane;
    const float* Dp = out + (size_t)(b * NCP) * plane;   // density plane (c=0)

    const int vr = tid >> 2;           // 0..63
    const int vc = (tid & 3) * 32;     // 0/32/64/96 (shorts)

    for (int y0 = 0; y0 < 384; y0 += 64) {
        int yy = y0 + vr; if (yy > NY - 1) yy = NY - 1;
        const unsigned short* Vrow = Vp + (size_t)yy * NH + vc;
        #pragma unroll
        for (int j = 0; j < 4; ++j)
            *(uint4*)&Bs2[vr * 136 + vc + j * 8] = *(const uint4*)&Vrow[j * 8];
        __syncthreads();

        f32x4 acc[2][2];
        #pragma unroll
        for (int i = 0; i < 2; ++i)
            #pragma unroll
            for (int j = 0; j < 2; ++j)
                acc[i][j] = (f32x4){0.f, 0.f, 0.f, 0.f};

        #pragma unroll
        for (int ki = 0; ki < 4; ++ki) {
            const int ko = ki * 32 + q * 8;
            short8 a0 = *(const short8*)&T[(mw2      + ln) * 136 + ko];
            short8 a1 = *(const short8*)&T[(mw2 + 16 + ln) * 136 + ko];
            short8 b0 = *(const short8*)&Bs2[(nw2      + ln) * 136 + ko];
            short8 b1 = *(const short8*)&Bs2[(nw2 + 16 + ln) * 136 + ko];
            acc[0][0] = __builtin_amdgcn_mfma_f32_16x16x32_bf16(a0, b0, acc[0][0], 0, 0, 0);
            acc[0][1] = __builtin_amdgcn_mfma_f32_16x16x32_bf16(a0, b1, acc[0][1], 0, 0, 0);
            acc[1][0] = __builtin_amdgcn_mfma_f32_16x16x32_bf16(a1, b0, acc[1][0], 0, 0, 0);
            acc[1][1] = __builtin_amdgcn_mfma_f32_16x16x32_bf16(a1, b1, acc[1][1], 0, 0, 0);
        }
        __syncthreads();   // Bs2 consumed; next iter may re-stage

        #pragma unroll
        for (int mi = 0; mi < 2; ++mi) {
            #pragma unroll
            for (int reg = 0; reg < 4; ++reg) {
                int x = x0 + mw2 + mi * 16 + q * 4 + reg;
                if (x < NX) {
                    size_t rowo = (size_t)x * NY;
                    #pragma unroll
                    for (int nj = 0; nj < 2; ++nj) {
                        int y = y0 + nw2 + nj * 16 + ln;
                        if (y < NY) {
                            float val = acc[mi][nj][reg];
                            if (DIV) {
                                float dv = Dp[rowo + y];
                                dv = fminf(fmaxf(dv, 1e-6f), 1e5f);
                                val /= dv;
                            }
                            Cp[rowo + y] = val;
                        }
                    }
                }
            }
        }
    }
}

extern "C" void kernel_launch(void* const* d_in, const int* in_sizes, int n_in,
                              void* d_out, int out_size, void* d_ws, size_t ws_size,
                              hipStream_t stream)
{
    const float* wt      = (const float*)d_in[0];
    const float* lon_in  = (const float*)d_in[1];
    const float* lat_in  = (const float*)d_in[2];
    const float* lon_out = (const float*)d_in[3];
    const float* lat_out = (const float*)d_in[4];
    const float* ls      = (const float*)d_in[5];
    float* out = (float*)d_out;

    // Workspace (ushort elements): w0t | w1t | wtT  — ~21 MB total (t eliminated)
    unsigned short* w0t = (unsigned short*)d_ws;
    unsigned short* w1t = w0t + (size_t)NB * NX * NW;            // 1,474,560
    unsigned short* wtT = w1t + (size_t)NB * NY * NH;            // +369,664

    rbf_w0_kernel<<<(NB * NX * NW) / 256, 256, 0, stream>>>(lon_in, lon_out, ls, w0t);
    rbf_w1_kernel<<<(NB * NY * NH) / 256, 256, 0, stream>>>(lat_in, lat_out, ls, w1t);

    dim3 g3(4, 1, NB * NCP);                 // 4 w-tiles x 264 (b,c)
    prep_wtT_kernel<<<g3, 256, 0, stream>>>(wt, wtT);

    dim3 gd(12, NB);                         // density plane first (c=0)
    fused_stage<false><<<gd, 256, 0, stream>>>(w0t, wtT, w1t, out);

    dim3 gm(12, NB * NC);                    // data channels, fused division
    fused_stage<true><<<gm, 256, 0, stream>>>(w0t, wtT, w1t, out);
}

// Round 2
// 505.050 us; speedup vs baseline: 1.0179x; 1.0179x over previous
//
#include <hip/hip_runtime.h>

// Dims
#define NB 8
#define NC 32
#define NCP 33
#define NW 256
#define NH 128
#define NX 720
#define NY 361

typedef __attribute__((ext_vector_type(8)))  short short8;
typedef __attribute__((ext_vector_type(16))) float f32x16;

// fp32 -> bf16 round-to-nearest-even
static __device__ __forceinline__ unsigned short f2bf(float f) {
    union { float f; unsigned int u; } v; v.f = f;
    unsigned int r = (v.u + 0x7FFFu + ((v.u >> 16) & 1u)) >> 16;
    return (unsigned short)r;
}

// K1: w0t[b][x][w] bf16
__global__ __launch_bounds__(256) void rbf_w0_kernel(
    const float* __restrict__ lon_in, const float* __restrict__ lon_out,
    const float* __restrict__ ls, unsigned short* __restrict__ w0t)
{
    int idx = blockIdx.x * 256 + threadIdx.x;   // exact grid: 8*720*256
    int w = idx & (NW - 1);
    int r = idx >> 8;
    int x = r % NX;
    int b = r / NX;
    float l = ls[0];
    float inv = -0.5f / (l * l);
    float d = lon_in[b * NW + w] - lon_out[b * NX + x];
    w0t[idx] = f2bf(__expf(inv * d * d));
}

// K2: w1t[b][y][h] bf16
__global__ __launch_bounds__(256) void rbf_w1_kernel(
    const float* __restrict__ lat_in, const float* __restrict__ lat_out,
    const float* __restrict__ ls, unsigned short* __restrict__ w1t)
{
    int idx = blockIdx.x * 256 + threadIdx.x;   // exact grid: 8*361*128
    int h = idx & (NH - 1);
    int r = idx >> 7;
    int y = r % NY;
    int b = r / NY;
    float l = ls[0];
    float inv = -0.5f / (l * l);
    float d = lat_in[b * NH + h] - lat_out[b * NY + y];
    w1t[idx] = f2bf(__expf(inv * d * d));
}

// K3: wtT[b][c(33)][h(128)][w(256)] bf16 — transposed, NaN-fixed, c=0 = density mask.
__global__ __launch_bounds__(256) void prep_wtT_kernel(
    const float* __restrict__ wt, unsigned short* __restrict__ wtT)
{
    __shared__ float tile[64 * 129];
    const int bc = blockIdx.z;
    const int b = bc / NCP;
    const int c = bc - b * NCP;
    const int w0 = blockIdx.x * 64;
    const bool dens = (c == 0);
    const float* src = wt + ((size_t)b * NC + (dens ? 0 : (c - 1))) * (NW * NH);

    const int r4 = threadIdx.x >> 5;   // 0..7
    const int c4 = threadIdx.x & 31;   // float4 col
    #pragma unroll
    for (int p = 0; p < 8; ++p) {
        int r = r4 + p * 8;
        float4 v = *(const float4*)&src[(size_t)(w0 + r) * NH + c4 * 4];
        float o0 = (v.x != v.x) ? 0.f : (dens ? 1.f : v.x);
        float o1 = (v.y != v.y) ? 0.f : (dens ? 1.f : v.y);
        float o2 = (v.z != v.z) ? 0.f : (dens ? 1.f : v.z);
        float o3 = (v.w != v.w) ? 0.f : (dens ? 1.f : v.w);
        float* tp = &tile[r * 129 + c4 * 4];
        tp[0] = o0; tp[1] = o1; tp[2] = o2; tp[3] = o3;
    }
    __syncthreads();

    unsigned short* dst = wtT + (size_t)bc * (NH * NW);
    #pragma unroll
    for (int p = 0; p < 4; ++p) {
        int ch = threadIdx.x + p * 256;
        int wc = ch & 7;          // which 8-w chunk in this 64-w tile
        int h  = ch >> 3;         // 0..127
        unsigned int u[4];
        #pragma unroll
        for (int j = 0; j < 4; ++j) {
            unsigned int lo = f2bf(tile[(wc * 8 + 2 * j    ) * 129 + h]);
            unsigned int hi = f2bf(tile[(wc * 8 + 2 * j + 1) * 129 + h]);
            u[j] = lo | (hi << 16);
        }
        uint4 q = make_uint4(u[0], u[1], u[2], u[3]);
        *(uint4*)&dst[(size_t)h * NW + w0 + wc * 8] = q;
    }
}

// Fused stage1+stage2, 32x32x16 MFMA everywhere.
// Phase 1: T[64][128] = w0t[b][x-tile][:256] * wtT[bc][:128][:256]^T  -> LDS (bf16)
//          A-operand in registers (double-buffered), only B staged in LDS.
// Phase 2: out[bc][x-tile][:361] = T * w1t[b][:361][:128]^T
// DIV=true : c=1..32, all 6 y-chunks, divide by clipped density. 1D grid 3072,
//            XCD-chunked so one bc's 12 x-tiles share an XCD L2.
// DIV=false: c=0 density plane, grid (12, 8, 6) — one y-chunk per block
//            (phase-1 recompute x6 is ~2 GF, cheap; kills the serial tail).
template <bool DIV>
__global__ __launch_bounds__(256, 4) void fused_stage(
    const unsigned short* __restrict__ w0t,
    const unsigned short* __restrict__ wtT,
    const unsigned short* __restrict__ w1t,
    float* __restrict__ out)
{
    __shared__ __align__(16) unsigned short T[64 * 136];   // 17,408 B
    __shared__ __align__(16) unsigned short S[128 * 72];   // 18,432 B (Bs p1 / Bs2 p2)

    int b, c, x0;
    if (DIV) {
        int id  = blockIdx.x;          // 0..3071
        int xcd = id & 7;
        int p   = id >> 3;             // 0..383
        int bcq = p / 12;              // 0..31
        int xt  = p - bcq * 12;        // 0..11
        int bcl = bcq * 8 + xcd;       // 0..255 (bijective)
        b  = bcl >> 5;
        c  = 1 + (bcl & 31);
        x0 = xt * 64;
    } else {
        b  = blockIdx.y;
        c  = 0;
        x0 = blockIdx.x * 64;
    }
    const int bc = b * NCP + c;

    const int tid  = threadIdx.x;
    const int lane = tid & 63;
    const int wv   = tid >> 6;
    const int l31  = lane & 31;
    const int lk   = lane >> 5;        // 0/1: k-half of 32x32 fragment

    const unsigned short* Ap = w0t + (size_t)b * NX * NW;
    const unsigned short* Bp = wtT + (size_t)bc * NH * NW;
    const unsigned short* Vp = w1t + (size_t)b * NY * NH;

    // ---------------- Phase 1 ----------------
    const int mw1 = (wv & 1) * 32;     // x quadrant (one 32-row m-tile)
    const int nh1 = (wv >> 1) * 64;    // h half (two 32-col n-tiles)

    int xrA = x0 + mw1 + l31; if (xrA > NX - 1) xrA = NX - 1;
    const unsigned short* Arow = Ap + (size_t)xrA * NW + lk * 8;

    f32x16 acc1[2];
    #pragma unroll
    for (int i = 0; i < 2; ++i)
        #pragma unroll
        for (int j = 0; j < 16; ++j) acc1[i][j] = 0.f;

    // A fragments: lane holds A[row=l31][k = k0 + ki*16 + lk*8 .. +8)
    short8 af0[4], af1[4];
    #pragma unroll
    for (int ki = 0; ki < 4; ++ki)
        af0[ki] = *(const short8*)&Arow[ki * 16];

    const int brr = tid >> 1;          // 0..127
    const int bcc = (tid & 1) * 32;    // 0/32 shorts

    #pragma unroll
    for (int k0i = 0; k0i < 4; ++k0i) {
        const int k0 = k0i * 64;
        // stage B tile [128 h-rows][64 k] into S (stride 72: 2-way max on reads)
        const unsigned short* Brow = Bp + (size_t)brr * NW + k0 + bcc;
        #pragma unroll
        for (int j = 0; j < 4; ++j)
            *(uint4*)&S[brr * 72 + bcc + j * 8] = *(const uint4*)&Brow[j * 8];
        __syncthreads();

        short8* cur = (k0i & 1) ? af1 : af0;   // folds: k0i is compile-time
        short8* nxt = (k0i & 1) ? af0 : af1;
        if (k0i < 3) {
            #pragma unroll
            for (int ki = 0; ki < 4; ++ki)
                nxt[ki] = *(const short8*)&Arow[k0 + 64 + ki * 16];
        }
        #pragma unroll
        for (int ki = 0; ki < 4; ++ki) {
            short8 b0 = *(const short8*)&S[(nh1      + l31) * 72 + ki * 16 + lk * 8];
            short8 b1 = *(const short8*)&S[(nh1 + 32 + l31) * 72 + ki * 16 + lk * 8];
            acc1[0] = __builtin_amdgcn_mfma_f32_32x32x16_bf16(cur[ki], b0, acc1[0], 0, 0, 0);
            acc1[1] = __builtin_amdgcn_mfma_f32_32x32x16_bf16(cur[ki], b1, acc1[1], 0, 0, 0);
        }
        __syncthreads();
    }

    // Write T quadrant from 32x32 C layout: row=(r&3)+8*(r>>2)+4*lk, col=l31.
    #pragma unroll
    for (int nn = 0; nn < 2; ++nn)
        #pragma unroll
        for (int r = 0; r < 16; ++r) {
            int rowf = (r & 3) + 8 * (r >> 2) + 4 * lk;
            T[(mw1 + rowf) * 136 + nh1 + nn * 32 + l31] = f2bf(acc1[nn][r]);
        }
    __syncthreads();

    // ---------------- Phase 2 ----------------
    const int mw2 = (wv & 1) * 32;
    const int nw2 = (wv >> 1) * 32;

    const size_t plane = (size_t)NX * NY;
    float* Cp = out + (size_t)bc * plane;
    const float* Dp = out + (size_t)(b * NCP) * plane;   // density plane (c=0)

    const int vr = tid >> 2;           // 0..63
    const int vc = (tid & 3) * 32;     // 0/32/64/96 shorts

    const int y_begin = DIV ? 0   : (int)blockIdx.z * 64;
    const int y_end   = DIV ? 384 : y_begin + 64;

    for (int y0 = y_begin; y0 < y_end; y0 += 64) {
        // stage w1t y-chunk [64 y-rows][128 k] into S (stride 136)
        int yy = y0 + vr; if (yy > NY - 1) yy = NY - 1;
        const unsigned short* Vrow = Vp + (size_t)yy * NH + vc;
        #pragma unroll
        for (int j = 0; j < 4; ++j)
            *(uint4*)&S[vr * 136 + vc + j * 8] = *(const uint4*)&Vrow[j * 8];
        __syncthreads();

        f32x16 acc;
        #pragma unroll
        for (int j = 0; j < 16; ++j) acc[j] = 0.f;

        #pragma unroll
        for (int ki = 0; ki < 8; ++ki) {
            short8 a  = *(const short8*)&T[(mw2 + l31) * 136 + ki * 16 + lk * 8];
            short8 bb = *(const short8*)&S[(nw2 + l31) * 136 + ki * 16 + lk * 8];
            acc = __builtin_amdgcn_mfma_f32_32x32x16_bf16(a, bb, acc, 0, 0, 0);
        }
        __syncthreads();   // S consumed before next stage

        // Epilogue: per store instruction = 2 contiguous 128B runs.
        // Loads issued in a separate loop BEFORE stores (out aliasing would
        // otherwise serialize load/store per element).
        const int ybase = y0 + nw2 + l31;
        float dv[16];
        if (DIV) {
            #pragma unroll
            for (int r = 0; r < 16; ++r) {
                int row = mw2 + (r & 3) + 8 * (r >> 2) + 4 * lk;
                int x = x0 + row;
                dv[r] = (x < NX && ybase < NY) ? Dp[(size_t)x * NY + ybase] : 1.f;
            }
        }
        #pragma unroll
        for (int r = 0; r < 16; ++r) {
            int row = mw2 + (r & 3) + 8 * (r >> 2) + 4 * lk;
            int x = x0 + row;
            if (x < NX && ybase < NY) {
                float val = acc[r];
                if (DIV) {
                    float d2 = fminf(fmaxf(dv[r], 1e-6f), 1e5f);
                    val /= d2;
                }
                Cp[(size_t)x * NY + ybase] = val;
            }
        }
    }
}

extern "C" void kernel_launch(void* const* d_in, const int* in_sizes, int n_in,
                              void* d_out, int out_size, void* d_ws, size_t ws_size,
                              hipStream_t stream)
{
    const float* wt      = (const float*)d_in[0];
    const float* lon_in  = (const float*)d_in[1];
    const float* lat_in  = (const float*)d_in[2];
    const float* lon_out = (const float*)d_in[3];
    const float* lat_out = (const float*)d_in[4];
    const float* ls      = (const float*)d_in[5];
    float* out = (float*)d_out;

    // Workspace (ushort elements): w0t | w1t | wtT — ~21 MB
    unsigned short* w0t = (unsigned short*)d_ws;
    unsigned short* w1t = w0t + (size_t)NB * NX * NW;
    unsigned short* wtT = w1t + (size_t)NB * NY * NH;

    rbf_w0_kernel<<<(NB * NX * NW) / 256, 256, 0, stream>>>(lon_in, lon_out, ls, w0t);
    rbf_w1_kernel<<<(NB * NY * NH) / 256, 256, 0, stream>>>(lat_in, lat_out, ls, w1t);

    dim3 g3(4, 1, NB * NCP);
    prep_wtT_kernel<<<g3, 256, 0, stream>>>(wt, wtT);

    dim3 gd(12, NB, 6);                      // density: one y-chunk per block
    fused_stage<false><<<gd, 256, 0, stream>>>(w0t, wtT, w1t, out);

    fused_stage<true><<<3072, 256, 0, stream>>>(w0t, wtT, w1t, out);
}